// Round 11
// baseline (905.878 us; speedup 1.0000x reference)
//
#include <hip/hip_runtime.h>

// ---------------- types / helpers ----------------
typedef float f32x4 __attribute__((ext_vector_type(4)));
typedef __bf16 bf16x8 __attribute__((ext_vector_type(8)));
typedef unsigned short ushort_t;
typedef ushort_t us4 __attribute__((ext_vector_type(4)));
typedef ushort_t us8 __attribute__((ext_vector_type(8)));

#define MFMA16(a, b, c) __builtin_amdgcn_mfma_f32_16x16x32_bf16((a), (b), (c), 0, 0, 0)

__device__ __forceinline__ ushort_t f2bf(float f) {
    unsigned int u = __builtin_bit_cast(unsigned int, f);
    u += 0x7fffu + ((u >> 16) & 1u);   // RNE
    return (ushort_t)(u >> 16);
}

__device__ __forceinline__ float gelu_fast(float x) {
    float x2 = x * x;
    float t = __builtin_fmaf(0.044715f * x2, x, x);
    float e = __builtin_amdgcn_exp2f(t * (-1.5957691216f * 1.44269504f));
    return x * __builtin_amdgcn_rcpf(1.0f + e);
}

// ---------------- problem constants ----------------
#define NTOK 98
#define CCH 96
#define QSCALE 0.17677669529663687f  // 1/sqrt(32)

// workspace byte offsets (weights + bias only)
#define WQKVP_OFF   ((size_t)0)
#define WPROJP_OFF  (WQKVP_OFF + (size_t)27648 * 2)
#define WFC1P_OFF   (WPROJP_OFF + (size_t)9216 * 2)
#define WFC2P_OFF   (WFC1P_OFF + (size_t)36864 * 2)
#define BIAS_OFF    (WFC2P_OFF + (size_t)36864 * 2)

// ---------------- K0: weight repack into MFMA B-fragment order + rel-pos bias ----------------
__global__ __launch_bounds__(256) void prep_kernel(
    const float* __restrict__ qkv_w, const float* __restrict__ proj_w,
    const float* __restrict__ fc1_w, const float* __restrict__ fc2_w,
    const float* __restrict__ rpb,
    ushort_t* __restrict__ wqkvP, ushort_t* __restrict__ wprojP,
    ushort_t* __restrict__ wfc1P, ushort_t* __restrict__ wfc2P,
    float* __restrict__ bias)
{
    int i = blockIdx.x * 256 + threadIdx.x;
    if (i < 27648) {  // qkv: f = ((h*3+w)*2+nt)*3+k0
        int f = i >> 9, r = i & 511, lane = r >> 3, m = r & 7;
        int k0 = f % 3, t = f / 3, nt = t % 2, t2 = t / 2, w = t2 % 3, h = t2 / 3;
        int row = k0 * 32 + (lane >> 4) * 8 + m;
        int col = w * 96 + h * 32 + nt * 16 + (lane & 15);
        wqkvP[i] = f2bf(qkv_w[row * 288 + col]);
        return;
    }
    i -= 27648;
    if (i < 9216) {   // proj: f = nt*3+k0
        int f = i >> 9, r = i & 511, lane = r >> 3, m = r & 7;
        int k0 = f % 3, nt = f / 3;
        int row = k0 * 32 + (lane >> 4) * 8 + m;
        int col = nt * 16 + (lane & 15);
        wprojP[i] = f2bf(proj_w[row * 96 + col]);
        return;
    }
    i -= 9216;
    if (i < 36864) {  // fc1
        int f = i >> 9, r = i & 511, lane = r >> 3, m = r & 7;
        int k0 = f % 3, nt = f / 3;
        int row = k0 * 32 + (lane >> 4) * 8 + m;
        int col = nt * 16 + (lane & 15);
        wfc1P[i] = f2bf(fc1_w[row * 384 + col]);
        return;
    }
    i -= 36864;
    if (i < 36864) {  // fc2
        int f = i >> 9, r = i & 511, lane = r >> 3, m = r & 7;
        int k0 = f % 12, nt = f / 12;
        int row = k0 * 32 + (lane >> 4) * 8 + m;
        int col = nt * 16 + (lane & 15);
        wfc2P[i] = f2bf(fc2_w[row * 96 + col]);
        return;
    }
    i -= 36864;
    if (i < 28812) {
        int h = i / 9604, rem = i % 9604, r = rem / 98, c = rem % 98;
        int rd = r / 49 - c / 49 + 1;
        int rh = (r % 49) / 7 - (c % 49) / 7 + 6;
        int rw = r % 7 - c % 7 + 6;
        int idx = (rd * 13 + rh) * 13 + rw;
        bias[i] = rpb[idx * 3 + h];
    }
}

// ---------------- K1: fused LN1 + QKV + attention + proj + residual ----------------
// one block = one window; 192 threads = 3 waves, wave = head. 2 barriers total.
// LDS: per-wave sc 6208 us: quick Q/K stage [0..575] -> vT [0..4351] ->
//      {P [0..2175] + out [2176..6207]} ; plus LN stats + n1 w/b + tokbase.
__global__ __launch_bounds__(192, 3) void fused_attn(
    const float* __restrict__ x, const float* __restrict__ mask,
    const float* __restrict__ n1w, const float* __restrict__ n1b,
    const float* __restrict__ qkv_b, const float* __restrict__ proj_b,
    const ushort_t* __restrict__ wqkvP, const ushort_t* __restrict__ wprojP,
    const float* __restrict__ bias, float* __restrict__ dout)
{
    __shared__ ushort_t sc_all[3][6208];   // 37,248 B
    __shared__ float    stats[112][2];     // mean, rstd per token
    __shared__ float    wb[192];           // n1w[0..95], n1b[96..191]
    __shared__ int      tokbase[112];

    const int tid  = threadIdx.x;
    const int lane = tid & 63;
    const int wave = tid >> 6;        // = head
    const int l16  = lane & 15, lg = lane >> 4;

    // swizzle: (wm, bb=0) and (wm, bb=1) are 8 blocks apart -> same XCD, adjacent in time
    const int b  = blockIdx.x;
    const int wm = (b & 7) * 256 + ((b >> 3) >> 1);
    const int bb = (b >> 3) & 1;
    const int id_ = wm >> 8, ih = (wm >> 4) & 15, iw = wm & 15;

    wb[tid] = (tid < 96) ? n1w[tid] : n1b[tid - 96];

    if (tid >= 98 && tid < 112) {
        int t = tid;
        stats[t][0] = 0.f; stats[t][1] = 0.f;   // pad rows: frag value = n1b (finite)
        int td = t / 49, r49 = t - td * 49, th = r49 / 7, tw = r49 - th * 7;
        int od = (id_ * 2 + td + 1) & 15;
        int oh = ih * 7 + th + 3; if (oh >= 112) oh -= 112;
        int ow = iw * 7 + tw + 3; if (ow >= 112) ow -= 112;
        tokbase[t] = ((((bb << 4) + od) * 112 + oh) * 112 + ow) * 96;
    }

    // ---------- phase 1: LN stats (mean, rstd) per token ----------
    {
        const int g = tid >> 5, lane32 = tid & 31;
        for (int t = g; t < 98; t += 6) {
            int td = t / 49, r49 = t - td * 49, th = r49 / 7, tw = r49 - th * 7;
            int od = (id_ * 2 + td + 1) & 15;
            int oh = ih * 7 + th + 3; if (oh >= 112) oh -= 112;
            int ow = iw * 7 + tw + 3; if (ow >= 112) ow -= 112;
            int base = ((((bb << 4) + od) * 112 + oh) * 112 + ow) * 96;
            const float* xp = x + base;
            float v0 = xp[lane32], v1 = xp[lane32 + 32], v2 = xp[lane32 + 64];
            float s = v0 + v1 + v2, sq = v0 * v0 + v1 * v1 + v2 * v2;
            #pragma unroll
            for (int m = 1; m < 32; m <<= 1) { s += __shfl_xor(s, m); sq += __shfl_xor(sq, m); }
            float mean = s * (1.0f / 96.0f);
            float var = sq * (1.0f / 96.0f) - mean * mean;
            float rs = rsqrtf(var + 1e-5f);
            if (lane32 == 0) {
                tokbase[t] = base;
                stats[t][0] = mean; stats[t][1] = rs;
            }
        }
    }
    __syncthreads();   // barrier 1

    const int h = wave;
    ushort_t* sc = sc_all[wave];
    const float* biash = bias + h * 9604;
    const float* maskw = mask + (size_t)wm * 9604;

    bf16x8 qf[7], kf[7], vf[2][4];

    // ---------- phase 2: QKV staging, LN applied inline on global x reads ----------
    #pragma unroll
    for (int which = 0; which < 3; ++which) {
        bf16x8 bw[2][3];
        float  bia[2];
        #pragma unroll
        for (int nt = 0; nt < 2; ++nt) {
            bia[nt] = qkv_b[which * 96 + h * 32 + nt * 16 + l16];
            #pragma unroll
            for (int k0 = 0; k0 < 3; ++k0)
                bw[nt][k0] = *(const bf16x8*)(wqkvP + ((((h * 3 + which) * 2 + nt) * 3 + k0) << 9) + lane * 8);
        }
        if (which == 2) {
            // zero vT pad cols 112..127 (rows 0..31) -> also zero-pads the P buffer
            us8 z = {0, 0, 0, 0, 0, 0, 0, 0};
            *(us8*)(sc + (lane >> 1) * 136 + 112 + (lane & 1) * 8) = z;
        }
        for (int mt = 0; mt < 7; ++mt) {
            const int r = mt * 16 + l16;
            const int base = tokbase[r];
            const float mean = stats[r][0], rs = stats[r][1];
            const float cadd = -mean * rs;
            bf16x8 af[3];
            #pragma unroll
            for (int k0 = 0; k0 < 3; ++k0) {
                const float* xp = x + base + k0 * 32 + lg * 8;
                f32x4 u0 = *(const f32x4*)xp;
                f32x4 u1 = *(const f32x4*)(xp + 4);
                const int ch = k0 * 32 + lg * 8;
                us8 pk;
                #pragma unroll
                for (int e = 0; e < 4; ++e) {
                    float val = __builtin_fmaf(u0[e], rs, cadd);
                    pk[e] = f2bf(__builtin_fmaf(val, wb[ch + e], wb[96 + ch + e]));
                }
                #pragma unroll
                for (int e = 0; e < 4; ++e) {
                    float val = __builtin_fmaf(u1[e], rs, cadd);
                    pk[4 + e] = f2bf(__builtin_fmaf(val, wb[ch + 4 + e], wb[96 + ch + 4 + e]));
                }
                af[k0] = __builtin_bit_cast(bf16x8, pk);
            }
            #pragma unroll
            for (int nt = 0; nt < 2; ++nt) {
                f32x4 acc = {0.f, 0.f, 0.f, 0.f};
                acc = MFMA16(af[0], bw[nt][0], acc);
                acc = MFMA16(af[1], bw[nt][1], acc);
                acc = MFMA16(af[2], bw[nt][2], acc);
                if (which == 2) {
                    us4 pk2;
                    #pragma unroll
                    for (int j = 0; j < 4; ++j) pk2[j] = f2bf(acc[j] + bia[nt]);
                    *(us4*)(sc + (nt * 16 + l16) * 136 + mt * 16 + lg * 4) = pk2;
                } else {
                    float scl = (which == 0) ? QSCALE : 1.0f;
                    #pragma unroll
                    for (int j = 0; j < 4; ++j)
                        sc[(lg * 4 + j) * 36 + nt * 16 + l16] = f2bf((acc[j] + bia[nt]) * scl);
                }
            }
            if (which == 0)      qf[mt] = *(const bf16x8*)(sc + l16 * 36 + lg * 8);
            else if (which == 1) kf[mt] = *(const bf16x8*)(sc + l16 * 36 + lg * 8);
        }
        if (which == 2) {
            #pragma unroll
            for (int nt2 = 0; nt2 < 2; ++nt2)
                #pragma unroll
                for (int k0 = 0; k0 < 4; ++k0)
                    vf[nt2][k0] = *(const bf16x8*)(sc + (nt2 * 16 + l16) * 136 + k0 * 32 + lg * 8);
        }
    }

    ushort_t* pbuf = sc;           // [16][136]: vT rows 0..15 (dead; pad cols zeroed)
    ushort_t* outh = sc + 2176;    // [112][36]: this head's 32 output channels

    // ---------- phase 3: attention (per-wave, no sync) ----------
    #pragma unroll
    for (int mt = 0; mt < 7; ++mt) {
        f32x4 sv[7];
        #pragma unroll
        for (int nt = 0; nt < 7; ++nt) {
            f32x4 z = {0.f, 0.f, 0.f, 0.f};
            sv[nt] = MFMA16(qf[mt], kf[nt], z);
        }
        const int r0 = mt * 16 + lg * 4;
        const bool ctail = (l16 < 2);   // col 96+l16 < 98
        #pragma unroll
        for (int j = 0; j < 4; ++j) {
            int r = r0 + j;
            if (r < 98) {
                const float* bp_ = biash + r * 98;
                const float* mp_ = maskw + r * 98;
                #pragma unroll
                for (int nt = 0; nt < 6; ++nt) {
                    int c = nt * 16 + l16;
                    sv[nt][j] += bp_[c] + mp_[c];
                }
                if (ctail) sv[6][j] += bp_[96 + l16] + mp_[96 + l16];
                else       sv[6][j] = -1e30f;
            } else {
                #pragma unroll
                for (int nt = 0; nt < 7; ++nt) sv[nt][j] = -1e30f;
            }
        }
        f32x4 inv;
        #pragma unroll
        for (int j = 0; j < 4; ++j) {
            float sum = 0.f;
            #pragma unroll
            for (int nt = 0; nt < 7; ++nt) { float e = __expf(sv[nt][j]); sv[nt][j] = e; sum += e; }
            sum += __shfl_xor(sum, 1); sum += __shfl_xor(sum, 2);
            sum += __shfl_xor(sum, 4); sum += __shfl_xor(sum, 8);
            inv[j] = __builtin_amdgcn_rcpf(sum);
        }
        #pragma unroll
        for (int j = 0; j < 4; ++j)
            #pragma unroll
            for (int nt = 0; nt < 7; ++nt)
                pbuf[(lg * 4 + j) * 136 + nt * 16 + l16] = f2bf(sv[nt][j]);
        bf16x8 pf[4];
        #pragma unroll
        for (int k0 = 0; k0 < 4; ++k0)
            pf[k0] = *(const bf16x8*)(pbuf + l16 * 136 + k0 * 32 + lg * 8);
        #pragma unroll
        for (int nt2 = 0; nt2 < 2; ++nt2) {
            f32x4 acc = {0.f, 0.f, 0.f, 0.f};
            #pragma unroll
            for (int k0 = 0; k0 < 4; ++k0) acc = MFMA16(pf[k0], vf[nt2][k0], acc);
            #pragma unroll
            for (int j = 0; j < 4; ++j) {
                int tok = mt * 16 + lg * 4 + j;
                if (tok < 98)
                    outh[tok * 36 + nt2 * 16 + l16] = f2bf(acc[j] * inv[j]);
            }
        }
    }
    __syncthreads();   // barrier 2

    // ---------- phase 4: proj + shortcut + scatter (42 jobs / 3 waves) ----------
    for (int job = wave; job < 42; job += 3) {
        int mt = job / 6, nt = job % 6;
        int cg = nt * 16 + l16;
        f32x4 acc = {0.f, 0.f, 0.f, 0.f};
        #pragma unroll
        for (int k0 = 0; k0 < 3; ++k0) {
            bf16x8 ao = *(const bf16x8*)(sc_all[k0] + 2176 + (mt * 16 + l16) * 36 + lg * 8);
            bf16x8 bp = *(const bf16x8*)(wprojP + ((nt * 3 + k0) << 9) + lane * 8);
            acc = MFMA16(ao, bp, acc);
        }
        float pb = proj_b[cg];
        #pragma unroll
        for (int j = 0; j < 4; ++j) {
            int tok = mt * 16 + lg * 4 + j;
            if (tok < 98) {
                int g = tokbase[tok] + cg;
                dout[g] = x[g] + acc[j] + pb;
            }
        }
    }
}

// ---------------- K3: LN2 + MLP + residual (in-place on d_out), 512 threads ----------------
__global__ __launch_bounds__(512, 2) void mlp_kernel(
    float* __restrict__ xres, const float* __restrict__ w2, const float* __restrict__ b2,
    const ushort_t* __restrict__ wfc1P, const float* __restrict__ fc1_b,
    const ushort_t* __restrict__ wfc2P, const float* __restrict__ fc2_b)
{
    __shared__ ushort_t A_ln[64 * 104];
    __shared__ ushort_t h_lds[64 * 392];
    const int tid = threadIdx.x;
    const int lane = tid & 63, wave = tid >> 6;
    const int l16 = lane & 15, lg = lane >> 4;
    const size_t t0 = (size_t)blockIdx.x * 64;

    {
        int t = tid >> 3, sub = tid & 7;
        const float* xp = xres + (t0 + t) * 96;
        f32x4 v[3];
        float s = 0.f, sq = 0.f;
        #pragma unroll
        for (int j4 = 0; j4 < 3; ++j4) {
            v[j4] = *(const f32x4*)(xp + (j4 * 8 + sub) * 4);
            #pragma unroll
            for (int e = 0; e < 4; ++e) { s += v[j4][e]; sq += v[j4][e] * v[j4][e]; }
        }
        s += __shfl_xor(s, 1); s += __shfl_xor(s, 2); s += __shfl_xor(s, 4);
        sq += __shfl_xor(sq, 1); sq += __shfl_xor(sq, 2); sq += __shfl_xor(sq, 4);
        float mean = s * (1.0f / 96.0f);
        float var = sq * (1.0f / 96.0f) - mean * mean;
        float rs = rsqrtf(var + 1e-5f);
        #pragma unroll
        for (int j4 = 0; j4 < 3; ++j4) {
            int c0 = (j4 * 8 + sub) * 4;
            us4 pk;
            #pragma unroll
            for (int e = 0; e < 4; ++e)
                pk[e] = f2bf((v[j4][e] - mean) * rs * w2[c0 + e] + b2[c0 + e]);
            *(us4*)(A_ln + t * 104 + c0) = pk;
        }
    }
    __syncthreads();

    for (int job = wave; job < 96; job += 8) {
        int mt = job / 24, nt = job % 24;
        int n = nt * 16 + l16;
        f32x4 acc = {0.f, 0.f, 0.f, 0.f};
        #pragma unroll
        for (int k0 = 0; k0 < 3; ++k0) {
            bf16x8 a  = *(const bf16x8*)(A_ln + (mt * 16 + l16) * 104 + k0 * 32 + lg * 8);
            bf16x8 bw = *(const bf16x8*)(wfc1P + ((nt * 3 + k0) << 9) + lane * 8);
            acc = MFMA16(a, bw, acc);
        }
        float bv = fc1_b[n];
        #pragma unroll
        for (int j = 0; j < 4; ++j) {
            int tok = mt * 16 + lg * 4 + j;
            h_lds[tok * 392 + n] = f2bf(gelu_fast(acc[j] + bv));
        }
    }
    __syncthreads();

    for (int job = wave; job < 24; job += 8) {
        int mt = job / 6, nt = job % 6;
        int c = nt * 16 + l16;
        f32x4 acc = {0.f, 0.f, 0.f, 0.f};
        #pragma unroll
        for (int k0 = 0; k0 < 12; ++k0) {
            bf16x8 a  = *(const bf16x8*)(h_lds + (mt * 16 + l16) * 392 + k0 * 32 + lg * 8);
            bf16x8 bw = *(const bf16x8*)(wfc2P + ((nt * 12 + k0) << 9) + lane * 8);
            acc = MFMA16(a, bw, acc);
        }
        float bv = fc2_b[c];
        #pragma unroll
        for (int j = 0; j < 4; ++j) {
            int tok = mt * 16 + lg * 4 + j;
            size_t g = (t0 + tok) * 96 + c;
            xres[g] = xres[g] + acc[j] + bv;
        }
    }
}

// ---------------- launcher ----------------
extern "C" void kernel_launch(void* const* d_in, const int* in_sizes, int n_in,
                              void* d_out, int out_size, void* d_ws, size_t ws_size,
                              hipStream_t stream) {
    const float* x      = (const float*)d_in[0];
    const float* mask   = (const float*)d_in[1];
    const float* n1w    = (const float*)d_in[2];
    const float* n1b    = (const float*)d_in[3];
    const float* qkv_w  = (const float*)d_in[4];
    const float* qkv_b  = (const float*)d_in[5];
    const float* rpb    = (const float*)d_in[6];
    const float* proj_w = (const float*)d_in[7];
    const float* proj_b = (const float*)d_in[8];
    const float* n2w    = (const float*)d_in[9];
    const float* n2b    = (const float*)d_in[10];
    const float* fc1_w  = (const float*)d_in[11];
    const float* fc1_b  = (const float*)d_in[12];
    const float* fc2_w  = (const float*)d_in[13];
    const float* fc2_b  = (const float*)d_in[14];

    char* ws = (char*)d_ws;
    ushort_t* wqkvP  = (ushort_t*)(ws + WQKVP_OFF);
    ushort_t* wprojP = (ushort_t*)(ws + WPROJP_OFF);
    ushort_t* wfc1P  = (ushort_t*)(ws + WFC1P_OFF);
    ushort_t* wfc2P  = (ushort_t*)(ws + WFC2P_OFF);
    float*    biasp  = (float*)(ws + BIAS_OFF);
    float*    dout   = (float*)d_out;

    prep_kernel<<<545, 256, 0, stream>>>(qkv_w, proj_w, fc1_w, fc2_w, rpb,
                                         wqkvP, wprojP, wfc1P, wfc2P, biasp);
    fused_attn<<<4096, 192, 0, stream>>>(x, mask, n1w, n1b, qkv_b, proj_b,
                                         wqkvP, wprojP, biasp, dout);
    mlp_kernel<<<6272, 512, 0, stream>>>(dout, n2w, n2b, wfc1P, fc1_b, wfc2P, fc2_b);
}

// Round 12
// 757.250 us; speedup vs baseline: 1.1963x; 1.1963x over previous
//
#include <hip/hip_runtime.h>

// ---------------- types / helpers ----------------
typedef float f32x4 __attribute__((ext_vector_type(4)));
typedef __bf16 bf16x8 __attribute__((ext_vector_type(8)));
typedef unsigned short ushort_t;
typedef ushort_t us4 __attribute__((ext_vector_type(4)));
typedef ushort_t us8 __attribute__((ext_vector_type(8)));

#define MFMA16(a, b, c) __builtin_amdgcn_mfma_f32_16x16x32_bf16((a), (b), (c), 0, 0, 0)

__device__ __forceinline__ ushort_t f2bf(float f) {
    unsigned int u = __builtin_bit_cast(unsigned int, f);
    u += 0x7fffu + ((u >> 16) & 1u);   // RNE
    return (ushort_t)(u >> 16);
}

__device__ __forceinline__ float gelu_fast(float x) {
    float x2 = x * x;
    float t = __builtin_fmaf(0.044715f * x2, x, x);
    float e = __builtin_amdgcn_exp2f(t * (-1.5957691216f * 1.44269504f));
    return x * __builtin_amdgcn_rcpf(1.0f + e);
}

// ---------------- problem constants ----------------
#define NTOK 98
#define CCH 96
#define QSCALE 0.17677669529663687f  // 1/sqrt(32)

// workspace byte offsets
#define WQKVP_OFF   ((size_t)0)
#define WPROJP_OFF  (WQKVP_OFF + (size_t)27648 * 2)
#define WFC1P_OFF   (WPROJP_OFF + (size_t)9216 * 2)
#define WFC2P_OFF   (WFC1P_OFF + (size_t)36864 * 2)
#define BIAS_OFF    (WFC2P_OFF + (size_t)36864 * 2)
#define XWG_OFF     (BIAS_OFF + (size_t)28812 * 4 + 256)          // [4096][112][96] bf16
#define XOG_OFF     (XWG_OFF + (size_t)4096 * 112 * 96 * 2 + 256) // [4096][112][96] bf16

// ---------------- K0: weight repack into MFMA B-fragment order + rel-pos bias ----------------
__global__ __launch_bounds__(256) void prep_kernel(
    const float* __restrict__ qkv_w, const float* __restrict__ proj_w,
    const float* __restrict__ fc1_w, const float* __restrict__ fc2_w,
    const float* __restrict__ rpb,
    ushort_t* __restrict__ wqkvP, ushort_t* __restrict__ wprojP,
    ushort_t* __restrict__ wfc1P, ushort_t* __restrict__ wfc2P,
    float* __restrict__ bias)
{
    int i = blockIdx.x * 256 + threadIdx.x;
    if (i < 27648) {  // qkv: f = ((h*3+w)*2+nt)*3+k0
        int f = i >> 9, r = i & 511, lane = r >> 3, m = r & 7;
        int k0 = f % 3, t = f / 3, nt = t % 2, t2 = t / 2, w = t2 % 3, h = t2 / 3;
        int row = k0 * 32 + (lane >> 4) * 8 + m;
        int col = w * 96 + h * 32 + nt * 16 + (lane & 15);
        wqkvP[i] = f2bf(qkv_w[row * 288 + col]);
        return;
    }
    i -= 27648;
    if (i < 9216) {   // proj: f = nt*3+k0
        int f = i >> 9, r = i & 511, lane = r >> 3, m = r & 7;
        int k0 = f % 3, nt = f / 3;
        int row = k0 * 32 + (lane >> 4) * 8 + m;
        int col = nt * 16 + (lane & 15);
        wprojP[i] = f2bf(proj_w[row * 96 + col]);
        return;
    }
    i -= 9216;
    if (i < 36864) {  // fc1
        int f = i >> 9, r = i & 511, lane = r >> 3, m = r & 7;
        int k0 = f % 3, nt = f / 3;
        int row = k0 * 32 + (lane >> 4) * 8 + m;
        int col = nt * 16 + (lane & 15);
        wfc1P[i] = f2bf(fc1_w[row * 384 + col]);
        return;
    }
    i -= 36864;
    if (i < 36864) {  // fc2
        int f = i >> 9, r = i & 511, lane = r >> 3, m = r & 7;
        int k0 = f % 12, nt = f / 12;
        int row = k0 * 32 + (lane >> 4) * 8 + m;
        int col = nt * 16 + (lane & 15);
        wfc2P[i] = f2bf(fc2_w[row * 96 + col]);
        return;
    }
    i -= 36864;
    if (i < 28812) {
        int h = i / 9604, rem = i % 9604, r = rem / 98, c = rem % 98;
        int rd = r / 49 - c / 49 + 1;
        int rh = (r % 49) / 7 - (c % 49) / 7 + 6;
        int rw = r % 7 - c % 7 + 6;
        int idx = (rd * 13 + rh) * 13 + rw;
        bias[i] = rpb[idx * 3 + h];
    }
}

// ---------------- K1: fused LN1 + QKV + attention + proj + residual ----------------
// one block = one window; 192 threads = 3 waves, wave = head. 2 barriers.
// LN'd tokens go to per-window global scratch xwg (L1/L2-hot, same CU writes+reads);
// head outputs go to xog; LDS is only per-head staging scratch (26.6 KB -> 5 blocks/CU).
__global__ __launch_bounds__(192, 4) void fused_attn(
    const float* __restrict__ x, const float* __restrict__ mask,
    const float* __restrict__ n1w, const float* __restrict__ n1b,
    const float* __restrict__ qkv_b, const float* __restrict__ proj_b,
    const ushort_t* __restrict__ wqkvP, const ushort_t* __restrict__ wprojP,
    const float* __restrict__ bias,
    ushort_t* __restrict__ xwg_all, ushort_t* __restrict__ xog_all,
    float* __restrict__ dout)
{
    __shared__ ushort_t sc_all[3][4352];   // per-head: Q/K quick stage -> vT -> P ping-pong
    __shared__ int tokbase[112];

    const int tid  = threadIdx.x;
    const int lane = tid & 63;
    const int wave = tid >> 6;        // = head
    const int l16  = lane & 15, lg = lane >> 4;

    // swizzle: (wm,bb=0) and (wm,bb=1) are 8 blocks apart -> same XCD, adjacent in time
    const int b  = blockIdx.x;
    const int wm = (b & 7) * 256 + (b >> 4);
    const int bb = (b >> 3) & 1;
    const int wid = (bb << 11) | wm;
    const int id_ = wm >> 8, ih = (wm >> 4) & 15, iw = wm & 15;

    ushort_t* xwg = xwg_all + (size_t)wid * (112 * 96);
    ushort_t* xog = xog_all + (size_t)wid * (112 * 96);

    if (tid < 98) {
        int td = tid / 49, r49 = tid - td * 49, th = r49 / 7, tw = r49 - th * 7;
        int od = (id_ * 2 + td + 1) & 15;
        int oh = ih * 7 + th + 3; if (oh >= 112) oh -= 112;
        int ow = iw * 7 + tw + 3; if (ow >= 112) ow -= 112;
        tokbase[tid] = ((((bb << 4) + od) * 112 + oh) * 112 + ow) * 96;
    }
    // zero pad rows 98..111 of xwg and xog (must be finite bf16 for frag reads)
    {
        us4 z4 = {0, 0, 0, 0};
        for (int i = tid; i < 336; i += 192) {
            int row = 98 + i / 24, c4 = (i % 24) * 4;
            *(us4*)(xwg + row * 96 + c4) = z4;
            *(us4*)(xog + row * 96 + c4) = z4;
        }
    }

    // ---------- phase 1: LN1 -> bf16 tokens in xwg ----------
    {
        const int g = tid >> 5, lane32 = tid & 31;
        for (int t = g; t < 98; t += 6) {
            int td = t / 49, r49 = t - td * 49, th = r49 / 7, tw = r49 - th * 7;
            int od = (id_ * 2 + td + 1) & 15;
            int oh = ih * 7 + th + 3; if (oh >= 112) oh -= 112;
            int ow = iw * 7 + tw + 3; if (ow >= 112) ow -= 112;
            int base = ((((bb << 4) + od) * 112 + oh) * 112 + ow) * 96;
            const float* xp = x + base;
            float v0 = xp[lane32], v1 = xp[lane32 + 32], v2 = xp[lane32 + 64];
            float s = v0 + v1 + v2, sq = v0 * v0 + v1 * v1 + v2 * v2;
            #pragma unroll
            for (int m = 1; m < 32; m <<= 1) { s += __shfl_xor(s, m); sq += __shfl_xor(sq, m); }
            float mean = s * (1.0f / 96.0f);
            float var = sq * (1.0f / 96.0f) - mean * mean;
            float rs = rsqrtf(var + 1e-5f);
            ushort_t* op = xwg + t * 96;
            op[lane32]      = f2bf((v0 - mean) * rs * n1w[lane32]      + n1b[lane32]);
            op[lane32 + 32] = f2bf((v1 - mean) * rs * n1w[lane32 + 32] + n1b[lane32 + 32]);
            op[lane32 + 64] = f2bf((v2 - mean) * rs * n1w[lane32 + 64] + n1b[lane32 + 64]);
        }
    }
    __syncthreads();   // barrier 1 (drains vmcnt: xwg visible block-wide via L2)

    const int h = wave;
    ushort_t* sc = sc_all[wave];
    const float* biash = bias + h * 9604;
    const float* maskw = mask + (size_t)wm * 9604;

    bf16x8 qf[7], kf[7], vf[2][4];

    // ---------- phase 2: per-head QKV staging (per-wave, no sync) ----------
    #pragma unroll
    for (int which = 0; which < 3; ++which) {
        bf16x8 bw[2][3];
        float  bia[2];
        #pragma unroll
        for (int nt = 0; nt < 2; ++nt) {
            bia[nt] = qkv_b[which * 96 + h * 32 + nt * 16 + l16];
            #pragma unroll
            for (int k0 = 0; k0 < 3; ++k0)
                bw[nt][k0] = *(const bf16x8*)(wqkvP + ((((h * 3 + which) * 2 + nt) * 3 + k0) << 9) + lane * 8);
        }
        if (which == 2) {
            // zero vT pad cols 112..127 (rows 0..31) -> also zero-pads both P buffers
            us8 z = {0, 0, 0, 0, 0, 0, 0, 0};
            *(us8*)(sc + (lane >> 1) * 136 + 112 + (lane & 1) * 8) = z;
        }
        for (int mt = 0; mt < 7; ++mt) {
            const ushort_t* ap = xwg + (mt * 16 + l16) * 96 + lg * 8;
            bf16x8 a0 = *(const bf16x8*)(ap);
            bf16x8 a1 = *(const bf16x8*)(ap + 32);
            bf16x8 a2 = *(const bf16x8*)(ap + 64);
            #pragma unroll
            for (int nt = 0; nt < 2; ++nt) {
                f32x4 acc = {0.f, 0.f, 0.f, 0.f};
                acc = MFMA16(a0, bw[nt][0], acc);
                acc = MFMA16(a1, bw[nt][1], acc);
                acc = MFMA16(a2, bw[nt][2], acc);
                if (which == 2) {
                    us4 pk;
                    #pragma unroll
                    for (int j = 0; j < 4; ++j) pk[j] = f2bf(acc[j] + bia[nt]);
                    *(us4*)(sc + (nt * 16 + l16) * 136 + mt * 16 + lg * 4) = pk;
                } else {
                    float scl = (which == 0) ? QSCALE : 1.0f;
                    #pragma unroll
                    for (int j = 0; j < 4; ++j)
                        sc[(lg * 4 + j) * 36 + nt * 16 + l16] = f2bf((acc[j] + bia[nt]) * scl);
                }
            }
            if (which == 0)      qf[mt] = *(const bf16x8*)(sc + l16 * 36 + lg * 8);
            else if (which == 1) kf[mt] = *(const bf16x8*)(sc + l16 * 36 + lg * 8);
        }
        if (which == 2) {
            #pragma unroll
            for (int nt2 = 0; nt2 < 2; ++nt2)
                #pragma unroll
                for (int k0 = 0; k0 < 4; ++k0)
                    vf[nt2][k0] = *(const bf16x8*)(sc + (nt2 * 16 + l16) * 136 + k0 * 32 + lg * 8);
        }
    }

    // ---------- phase 3: attention (per-wave, no sync); P ping-pong across mt ----------
    #pragma unroll
    for (int mt = 0; mt < 7; ++mt) {
        ushort_t* pbuf = sc + (mt & 1) * 2176;
        f32x4 sv[7];
        #pragma unroll
        for (int nt = 0; nt < 7; ++nt) {
            f32x4 z = {0.f, 0.f, 0.f, 0.f};
            sv[nt] = MFMA16(qf[mt], kf[nt], z);
        }
        const int r0 = mt * 16 + lg * 4;
        const bool ctail = (l16 < 2);   // col 96+l16 < 98
        #pragma unroll
        for (int j = 0; j < 4; ++j) {
            int r = r0 + j;
            if (r < 98) {
                const float* bp_ = biash + r * 98;
                const float* mp_ = maskw + r * 98;
                #pragma unroll
                for (int nt = 0; nt < 6; ++nt) {
                    int c = nt * 16 + l16;
                    sv[nt][j] += bp_[c] + mp_[c];
                }
                if (ctail) sv[6][j] += bp_[96 + l16] + mp_[96 + l16];
                else       sv[6][j] = -1e30f;
            } else {
                #pragma unroll
                for (int nt = 0; nt < 7; ++nt) sv[nt][j] = -1e30f;
            }
        }
        f32x4 inv;
        #pragma unroll
        for (int j = 0; j < 4; ++j) {
            float sum = 0.f;
            #pragma unroll
            for (int nt = 0; nt < 7; ++nt) { float e = __expf(sv[nt][j]); sv[nt][j] = e; sum += e; }
            sum += __shfl_xor(sum, 1); sum += __shfl_xor(sum, 2);
            sum += __shfl_xor(sum, 4); sum += __shfl_xor(sum, 8);
            inv[j] = __builtin_amdgcn_rcpf(sum);
        }
        #pragma unroll
        for (int j = 0; j < 4; ++j)
            #pragma unroll
            for (int nt = 0; nt < 7; ++nt)
                pbuf[(lg * 4 + j) * 136 + nt * 16 + l16] = f2bf(sv[nt][j]);
        bf16x8 pf[4];
        #pragma unroll
        for (int k0 = 0; k0 < 4; ++k0)
            pf[k0] = *(const bf16x8*)(pbuf + l16 * 136 + k0 * 32 + lg * 8);
        #pragma unroll
        for (int nt2 = 0; nt2 < 2; ++nt2) {
            f32x4 acc = {0.f, 0.f, 0.f, 0.f};
            #pragma unroll
            for (int k0 = 0; k0 < 4; ++k0) acc = MFMA16(pf[k0], vf[nt2][k0], acc);
            #pragma unroll
            for (int j = 0; j < 4; ++j) {
                int tok = mt * 16 + lg * 4 + j;
                if (tok < 98)
                    xog[tok * 96 + h * 32 + nt2 * 16 + l16] = f2bf(acc[j] * inv[j]);
            }
        }
    }
    __syncthreads();   // barrier 2 (drains vmcnt: xog visible block-wide)

    // ---------- phase 4: proj + shortcut + scatter (42 jobs / 3 waves) ----------
    for (int job = wave; job < 42; job += 3) {
        int mt = job / 6, nt = job % 6;
        int cg = nt * 16 + l16;
        f32x4 acc = {0.f, 0.f, 0.f, 0.f};
        #pragma unroll
        for (int k0 = 0; k0 < 3; ++k0) {
            bf16x8 ao = *(const bf16x8*)(xog + (mt * 16 + l16) * 96 + k0 * 32 + lg * 8);
            bf16x8 bp = *(const bf16x8*)(wprojP + ((nt * 3 + k0) << 9) + lane * 8);
            acc = MFMA16(ao, bp, acc);
        }
        float pb = proj_b[cg];
        #pragma unroll
        for (int j = 0; j < 4; ++j) {
            int tok = mt * 16 + lg * 4 + j;
            if (tok < 98) {
                int g = tokbase[tok] + cg;
                dout[g] = x[g] + acc[j] + pb;
            }
        }
    }
}

// ---------------- K3: LN2 + MLP + residual (in-place on d_out), 512 threads ----------------
__global__ __launch_bounds__(512, 2) void mlp_kernel(
    float* __restrict__ xres, const float* __restrict__ w2, const float* __restrict__ b2,
    const ushort_t* __restrict__ wfc1P, const float* __restrict__ fc1_b,
    const ushort_t* __restrict__ wfc2P, const float* __restrict__ fc2_b)
{
    __shared__ ushort_t A_ln[64 * 104];
    __shared__ ushort_t h_lds[64 * 392];
    const int tid = threadIdx.x;
    const int lane = tid & 63, wave = tid >> 6;
    const int l16 = lane & 15, lg = lane >> 4;
    const size_t t0 = (size_t)blockIdx.x * 64;

    {
        int t = tid >> 3, sub = tid & 7;
        const float* xp = xres + (t0 + t) * 96;
        f32x4 v[3];
        float s = 0.f, sq = 0.f;
        #pragma unroll
        for (int j4 = 0; j4 < 3; ++j4) {
            v[j4] = *(const f32x4*)(xp + (j4 * 8 + sub) * 4);
            #pragma unroll
            for (int e = 0; e < 4; ++e) { s += v[j4][e]; sq += v[j4][e] * v[j4][e]; }
        }
        s += __shfl_xor(s, 1); s += __shfl_xor(s, 2); s += __shfl_xor(s, 4);
        sq += __shfl_xor(sq, 1); sq += __shfl_xor(sq, 2); sq += __shfl_xor(sq, 4);
        float mean = s * (1.0f / 96.0f);
        float var = sq * (1.0f / 96.0f) - mean * mean;
        float rs = rsqrtf(var + 1e-5f);
        #pragma unroll
        for (int j4 = 0; j4 < 3; ++j4) {
            int c0 = (j4 * 8 + sub) * 4;
            us4 pk;
            #pragma unroll
            for (int e = 0; e < 4; ++e)
                pk[e] = f2bf((v[j4][e] - mean) * rs * w2[c0 + e] + b2[c0 + e]);
            *(us4*)(A_ln + t * 104 + c0) = pk;
        }
    }
    __syncthreads();

    for (int job = wave; job < 96; job += 8) {
        int mt = job / 24, nt = job % 24;
        int n = nt * 16 + l16;
        f32x4 acc = {0.f, 0.f, 0.f, 0.f};
        #pragma unroll
        for (int k0 = 0; k0 < 3; ++k0) {
            bf16x8 a  = *(const bf16x8*)(A_ln + (mt * 16 + l16) * 104 + k0 * 32 + lg * 8);
            bf16x8 bw = *(const bf16x8*)(wfc1P + ((nt * 3 + k0) << 9) + lane * 8);
            acc = MFMA16(a, bw, acc);
        }
        float bv = fc1_b[n];
        #pragma unroll
        for (int j = 0; j < 4; ++j) {
            int tok = mt * 16 + lg * 4 + j;
            h_lds[tok * 392 + n] = f2bf(gelu_fast(acc[j] + bv));
        }
    }
    __syncthreads();

    for (int job = wave; job < 24; job += 8) {
        int mt = job / 6, nt = job % 6;
        int c = nt * 16 + l16;
        f32x4 acc = {0.f, 0.f, 0.f, 0.f};
        #pragma unroll
        for (int k0 = 0; k0 < 12; ++k0) {
            bf16x8 a  = *(const bf16x8*)(h_lds + (mt * 16 + l16) * 392 + k0 * 32 + lg * 8);
            bf16x8 bw = *(const bf16x8*)(wfc2P + ((nt * 12 + k0) << 9) + lane * 8);
            acc = MFMA16(a, bw, acc);
        }
        float bv = fc2_b[c];
        #pragma unroll
        for (int j = 0; j < 4; ++j) {
            int tok = mt * 16 + lg * 4 + j;
            size_t g = (t0 + tok) * 96 + c;
            xres[g] = xres[g] + acc[j] + bv;
        }
    }
}

// ---------------- launcher ----------------
extern "C" void kernel_launch(void* const* d_in, const int* in_sizes, int n_in,
                              void* d_out, int out_size, void* d_ws, size_t ws_size,
                              hipStream_t stream) {
    const float* x      = (const float*)d_in[0];
    const float* mask   = (const float*)d_in[1];
    const float* n1w    = (const float*)d_in[2];
    const float* n1b    = (const float*)d_in[3];
    const float* qkv_w  = (const float*)d_in[4];
    const float* qkv_b  = (const float*)d_in[5];
    const float* rpb    = (const float*)d_in[6];
    const float* proj_w = (const float*)d_in[7];
    const float* proj_b = (const float*)d_in[8];
    const float* n2w    = (const float*)d_in[9];
    const float* n2b    = (const float*)d_in[10];
    const float* fc1_w  = (const float*)d_in[11];
    const float* fc1_b  = (const float*)d_in[12];
    const float* fc2_w  = (const float*)d_in[13];
    const float* fc2_b  = (const float*)d_in[14];

    char* ws = (char*)d_ws;
    ushort_t* wqkvP  = (ushort_t*)(ws + WQKVP_OFF);
    ushort_t* wprojP = (ushort_t*)(ws + WPROJP_OFF);
    ushort_t* wfc1P  = (ushort_t*)(ws + WFC1P_OFF);
    ushort_t* wfc2P  = (ushort_t*)(ws + WFC2P_OFF);
    float*    biasp  = (float*)(ws + BIAS_OFF);
    ushort_t* xwg    = (ushort_t*)(ws + XWG_OFF);
    ushort_t* xog    = (ushort_t*)(ws + XOG_OFF);
    float*    dout   = (float*)d_out;

    prep_kernel<<<545, 256, 0, stream>>>(qkv_w, proj_w, fc1_w, fc2_w, rpb,
                                         wqkvP, wprojP, wfc1P, wfc2P, biasp);
    fused_attn<<<4096, 192, 0, stream>>>(x, mask, n1w, n1b, qkv_b, proj_b,
                                         wqkvP, wprojP, biasp, xwg, xog, dout);
    mlp_kernel<<<6272, 512, 0, stream>>>(dout, n2w, n2b, wfc1P, fc1_b, wfc2P, fc2_b);
}

// Round 13
// 571.816 us; speedup vs baseline: 1.5842x; 1.3243x over previous
//
#include <hip/hip_runtime.h>

// ---------------- types / helpers ----------------
typedef float f32x4 __attribute__((ext_vector_type(4)));
typedef __bf16 bf16x8 __attribute__((ext_vector_type(8)));
typedef unsigned short ushort_t;
typedef ushort_t us4 __attribute__((ext_vector_type(4)));
typedef ushort_t us8 __attribute__((ext_vector_type(8)));
typedef unsigned int u32x4 __attribute__((ext_vector_type(4)));

#define MFMA16(a, b, c) __builtin_amdgcn_mfma_f32_16x16x32_bf16((a), (b), (c), 0, 0, 0)

__device__ __forceinline__ ushort_t f2bf(float f) {
    unsigned int u = __builtin_bit_cast(unsigned int, f);
    u += 0x7fffu + ((u >> 16) & 1u);   // RNE
    return (ushort_t)(u >> 16);
}

__device__ __forceinline__ unsigned int packbf2(float lo, float hi) {
    return ((unsigned int)f2bf(hi) << 16) | (unsigned int)f2bf(lo);
}

__device__ __forceinline__ float gelu_fast(float x) {
    float x2 = x * x;
    float t = __builtin_fmaf(0.044715f * x2, x, x);
    float e = __builtin_amdgcn_exp2f(t * (-1.5957691216f * 1.44269504f));
    return x * __builtin_amdgcn_rcpf(1.0f + e);
}

// ---------------- problem constants ----------------
#define NTOK 98
#define CCH 96
#define QSCALE 0.17677669529663687f  // 1/sqrt(32)

// workspace byte offsets (weights + bias only)
#define WQKVP_OFF   ((size_t)0)
#define WPROJP_OFF  (WQKVP_OFF + (size_t)27648 * 2)
#define WFC1P_OFF   (WPROJP_OFF + (size_t)9216 * 2)
#define WFC2P_OFF   (WFC1P_OFF + (size_t)36864 * 2)
#define BIAS_OFF    (WFC2P_OFF + (size_t)36864 * 2)

// ---------------- K0: weight repack into MFMA B-fragment order + rel-pos bias ----------------
__global__ __launch_bounds__(256) void prep_kernel(
    const float* __restrict__ qkv_w, const float* __restrict__ proj_w,
    const float* __restrict__ fc1_w, const float* __restrict__ fc2_w,
    const float* __restrict__ rpb,
    ushort_t* __restrict__ wqkvP, ushort_t* __restrict__ wprojP,
    ushort_t* __restrict__ wfc1P, ushort_t* __restrict__ wfc2P,
    float* __restrict__ bias)
{
    int i = blockIdx.x * 256 + threadIdx.x;
    if (i < 27648) {  // qkv: f = ((h*3+w)*2+nt)*3+k0
        int f = i >> 9, r = i & 511, lane = r >> 3, m = r & 7;
        int k0 = f % 3, t = f / 3, nt = t % 2, t2 = t / 2, w = t2 % 3, h = t2 / 3;
        int row = k0 * 32 + (lane >> 4) * 8 + m;
        int col = w * 96 + h * 32 + nt * 16 + (lane & 15);
        wqkvP[i] = f2bf(qkv_w[row * 288 + col]);
        return;
    }
    i -= 27648;
    if (i < 9216) {   // proj: f = nt*3+k0
        int f = i >> 9, r = i & 511, lane = r >> 3, m = r & 7;
        int k0 = f % 3, nt = f / 3;
        int row = k0 * 32 + (lane >> 4) * 8 + m;
        int col = nt * 16 + (lane & 15);
        wprojP[i] = f2bf(proj_w[row * 96 + col]);
        return;
    }
    i -= 9216;
    if (i < 36864) {  // fc1
        int f = i >> 9, r = i & 511, lane = r >> 3, m = r & 7;
        int k0 = f % 3, nt = f / 3;
        int row = k0 * 32 + (lane >> 4) * 8 + m;
        int col = nt * 16 + (lane & 15);
        wfc1P[i] = f2bf(fc1_w[row * 384 + col]);
        return;
    }
    i -= 36864;
    if (i < 36864) {  // fc2
        int f = i >> 9, r = i & 511, lane = r >> 3, m = r & 7;
        int k0 = f % 12, nt = f / 12;
        int row = k0 * 32 + (lane >> 4) * 8 + m;
        int col = nt * 16 + (lane & 15);
        wfc2P[i] = f2bf(fc2_w[row * 96 + col]);
        return;
    }
    i -= 36864;
    if (i < 28812) {
        int h = i / 9604, rem = i % 9604, r = rem / 98, c = rem % 98;
        int rd = r / 49 - c / 49 + 1;
        int rh = (r % 49) / 7 - (c % 49) / 7 + 6;
        int rw = r % 7 - c % 7 + 6;
        int idx = (rd * 13 + rh) * 13 + rw;
        bias[i] = rpb[idx * 3 + h];
    }
}

// ---------------- K1: fused LN1 + QKV + attention + proj + residual ----------------
// one block = one window; 192 threads = 3 waves, wave = head. 3 barriers.
// LDS: xw_lds [112][104] (LN'd tokens; aliased as attn-out after phase 2),
//      per-head sc 2176 us (Q/K quick-stage 576 aliased with single P [16][136]).
// V never touches LDS: natural-layout V MFMA outputs are routed to PV B-fragments
// with column-local __shfl (lane l16 = d-channel on both sides).
__global__ __launch_bounds__(192, 3) void fused_attn(
    const float* __restrict__ x, const float* __restrict__ mask,
    const float* __restrict__ n1w, const float* __restrict__ n1b,
    const float* __restrict__ qkv_b, const float* __restrict__ proj_b,
    const ushort_t* __restrict__ wqkvP, const ushort_t* __restrict__ wprojP,
    const float* __restrict__ bias, float* __restrict__ dout)
{
    __shared__ ushort_t xw_lds[112 * 104];   // 23,296 B
    __shared__ ushort_t sc_all[3][2176];     // 13,056 B
    __shared__ int tokbase[112];

    const int tid  = threadIdx.x;
    const int lane = tid & 63;
    const int wave = tid >> 6;        // = head
    const int l16  = lane & 15, lg = lane >> 4;

    // swizzle: (wm, bb=0) and (wm, bb=1) are 8 blocks apart -> same XCD, adjacent in time
    const int b  = blockIdx.x;
    const int wm = (b & 7) * 256 + ((b >> 3) >> 1);
    const int bb = (b >> 3) & 1;
    const int id_ = wm >> 8, ih = (wm >> 4) & 15, iw = wm & 15;

    if (tid < 98) {
        int td = tid / 49, r49 = tid - td * 49, th = r49 / 7, tw = r49 - th * 7;
        int od = (id_ * 2 + td + 1) & 15;
        int oh = ih * 7 + th + 3; if (oh >= 112) oh -= 112;
        int ow = iw * 7 + tw + 3; if (ow >= 112) ow -= 112;
        tokbase[tid] = ((((bb << 4) + od) * 112 + oh) * 112 + ow) * 96;
    }
    // zero pad token rows 98..111 (uninitialized LDS can decode as bf16 NaN)
    {
        us4 z4 = {0, 0, 0, 0};
        for (int i = tid; i < 14 * 26; i += 192) {
            int t = 98 + i / 26, c4 = (i % 26) * 4;
            *(us4*)(xw_lds + t * 104 + c4) = z4;
        }
    }
    __syncthreads();

    // ---------- phase 1: LN1 -> bf16 tokens in LDS ----------
    {
        const int g = tid >> 5, lane32 = tid & 31;
        for (int t = g; t < 98; t += 6) {
            const float* xp = x + tokbase[t];
            float v0 = xp[lane32], v1 = xp[lane32 + 32], v2 = xp[lane32 + 64];
            float s = v0 + v1 + v2, sq = v0 * v0 + v1 * v1 + v2 * v2;
            #pragma unroll
            for (int m = 1; m < 32; m <<= 1) { s += __shfl_xor(s, m); sq += __shfl_xor(sq, m); }
            float mean = s * (1.0f / 96.0f);
            float var = sq * (1.0f / 96.0f) - mean * mean;
            float rs = rsqrtf(var + 1e-5f);
            ushort_t* op = xw_lds + t * 104;
            op[lane32]      = f2bf((v0 - mean) * rs * n1w[lane32]      + n1b[lane32]);
            op[lane32 + 32] = f2bf((v1 - mean) * rs * n1w[lane32 + 32] + n1b[lane32 + 32]);
            op[lane32 + 64] = f2bf((v2 - mean) * rs * n1w[lane32 + 64] + n1b[lane32 + 64]);
        }
    }
    __syncthreads();

    const int h = wave;
    ushort_t* sc = sc_all[wave];
    const float* biash = bias + h * 9604;
    const float* maskw = mask + (size_t)wm * 9604;

    bf16x8 qf[7], kf[7], vf[2][4];

    // ---------- phase 2a/2b: Q and K via per-mt quick LDS staging ----------
    #pragma unroll
    for (int which = 0; which < 2; ++which) {
        bf16x8 bw[2][3];
        float  bia[2];
        #pragma unroll
        for (int nt = 0; nt < 2; ++nt) {
            bia[nt] = qkv_b[which * 96 + h * 32 + nt * 16 + l16];
            #pragma unroll
            for (int k0 = 0; k0 < 3; ++k0)
                bw[nt][k0] = *(const bf16x8*)(wqkvP + ((((h * 3 + which) * 2 + nt) * 3 + k0) << 9) + lane * 8);
        }
        for (int mt = 0; mt < 7; ++mt) {
            const ushort_t* ap = xw_lds + (mt * 16 + l16) * 104 + lg * 8;
            bf16x8 a0 = *(const bf16x8*)(ap);
            bf16x8 a1 = *(const bf16x8*)(ap + 32);
            bf16x8 a2 = *(const bf16x8*)(ap + 64);
            #pragma unroll
            for (int nt = 0; nt < 2; ++nt) {
                f32x4 acc = {0.f, 0.f, 0.f, 0.f};
                acc = MFMA16(a0, bw[nt][0], acc);
                acc = MFMA16(a1, bw[nt][1], acc);
                acc = MFMA16(a2, bw[nt][2], acc);
                float scl = (which == 0) ? QSCALE : 1.0f;
                #pragma unroll
                for (int j = 0; j < 4; ++j)
                    sc[(lg * 4 + j) * 36 + nt * 16 + l16] = f2bf((acc[j] + bia[nt]) * scl);
            }
            if (which == 0) qf[mt] = *(const bf16x8*)(sc + l16 * 36 + lg * 8);
            else            kf[mt] = *(const bf16x8*)(sc + l16 * 36 + lg * 8);
        }
    }

    // ---------- phase 2c: V natural-layout MFMA -> PV B-frags via column-local shuffles ----------
    {
        bf16x8 bw[2][3];
        float  bia[2];
        #pragma unroll
        for (int nt = 0; nt < 2; ++nt) {
            bia[nt] = qkv_b[192 + h * 32 + nt * 16 + l16];
            #pragma unroll
            for (int k0 = 0; k0 < 3; ++k0)
                bw[nt][k0] = *(const bf16x8*)(wqkvP + ((((h * 3 + 2) * 2 + nt) * 3 + k0) << 9) + lane * 8);
        }
        #pragma unroll
        for (int k0 = 0; k0 < 4; ++k0) {
            unsigned int pk[2][2][2];   // [half][nt2][pair]
            #pragma unroll
            for (int half = 0; half < 2; ++half) {
                int mtp = 2 * k0 + half;   // token tile 0..7; tile 7 = rows 112.. none (only 0..6 valid)
                if (mtp < 7) {
                    const ushort_t* ap = xw_lds + (mtp * 16 + l16) * 104 + lg * 8;
                    bf16x8 a0 = *(const bf16x8*)(ap);
                    bf16x8 a1 = *(const bf16x8*)(ap + 32);
                    bf16x8 a2 = *(const bf16x8*)(ap + 64);
                    #pragma unroll
                    for (int nt2 = 0; nt2 < 2; ++nt2) {
                        f32x4 acc = {0.f, 0.f, 0.f, 0.f};
                        acc = MFMA16(a0, bw[nt2][0], acc);
                        acc = MFMA16(a1, bw[nt2][1], acc);
                        acc = MFMA16(a2, bw[nt2][2], acc);
                        pk[half][nt2][0] = packbf2(acc[0] + bia[nt2], acc[1] + bia[nt2]);
                        pk[half][nt2][1] = packbf2(acc[2] + bia[nt2], acc[3] + bia[nt2]);
                    }
                } else {
                    // tokens 112..127: zero (P cols there are zero anyway; keep finite)
                    pk[half][0][0] = pk[half][0][1] = 0u;
                    pk[half][1][0] = pk[half][1][1] = 0u;
                }
            }
            // distribute: dest (l16, lg) elem m of vf[nt2][k0] = V[k0*32+lg*8+m][nt2*16+l16]
            #pragma unroll
            for (int nt2 = 0; nt2 < 2; ++nt2) {
                u32x4 w;
                #pragma unroll
                for (int e = 0; e < 4; ++e) {
                    int s = l16 + 16 * (2 * (lg & 1) + (e >> 1));
                    unsigned int t0 = (unsigned int)__shfl((int)pk[0][nt2][e & 1], s, 64);
                    unsigned int t1 = (unsigned int)__shfl((int)pk[1][nt2][e & 1], s, 64);
                    w[e] = (lg >> 1) ? t1 : t0;
                }
                vf[nt2][k0] = __builtin_bit_cast(bf16x8, w);
            }
        }
    }
    __syncthreads();   // all xw reads done -> xw_lds aliases as attn-out

    ushort_t* out = xw_lds;  // [112][104], cols 0..95; rows 98..111 remain zero

    // zero P pad cols 112..127 (rows 0..15) in own scratch (quick-stage region now dead)
    if (lane < 32) {
        us8 z = {0, 0, 0, 0, 0, 0, 0, 0};
        *(us8*)(sc + (lane >> 1) * 136 + 112 + (lane & 1) * 8) = z;
    }

    // ---------- phase 3: attention (per-wave, no sync); single P buffer ----------
    #pragma unroll
    for (int mt = 0; mt < 7; ++mt) {
        f32x4 sv[7];
        #pragma unroll
        for (int nt = 0; nt < 7; ++nt) {
            f32x4 z = {0.f, 0.f, 0.f, 0.f};
            sv[nt] = MFMA16(qf[mt], kf[nt], z);
        }
        const int r0 = mt * 16 + lg * 4;
        const bool ctail = (l16 < 2);   // col 96+l16 < 98
        #pragma unroll
        for (int j = 0; j < 4; ++j) {
            int r = r0 + j;
            if (r < 98) {
                const float* bp_ = biash + r * 98;
                const float* mp_ = maskw + r * 98;
                #pragma unroll
                for (int nt = 0; nt < 6; ++nt) {
                    int c = nt * 16 + l16;
                    sv[nt][j] += bp_[c] + mp_[c];
                }
                if (ctail) sv[6][j] += bp_[96 + l16] + mp_[96 + l16];
                else       sv[6][j] = -1e30f;
            } else {
                #pragma unroll
                for (int nt = 0; nt < 7; ++nt) sv[nt][j] = -1e30f;
            }
        }
        f32x4 inv;
        #pragma unroll
        for (int j = 0; j < 4; ++j) {
            float sum = 0.f;
            #pragma unroll
            for (int nt = 0; nt < 7; ++nt) { float e = __expf(sv[nt][j]); sv[nt][j] = e; sum += e; }
            sum += __shfl_xor(sum, 1); sum += __shfl_xor(sum, 2);
            sum += __shfl_xor(sum, 4); sum += __shfl_xor(sum, 8);
            inv[j] = __builtin_amdgcn_rcpf(sum);
        }
        #pragma unroll
        for (int j = 0; j < 4; ++j)
            #pragma unroll
            for (int nt = 0; nt < 7; ++nt)
                sc[(lg * 4 + j) * 136 + nt * 16 + l16] = f2bf(sv[nt][j]);
        bf16x8 pf[4];
        #pragma unroll
        for (int k0 = 0; k0 < 4; ++k0)
            pf[k0] = *(const bf16x8*)(sc + l16 * 136 + k0 * 32 + lg * 8);
        #pragma unroll
        for (int nt2 = 0; nt2 < 2; ++nt2) {
            f32x4 acc = {0.f, 0.f, 0.f, 0.f};
            #pragma unroll
            for (int k0 = 0; k0 < 4; ++k0) acc = MFMA16(pf[k0], vf[nt2][k0], acc);
            #pragma unroll
            for (int j = 0; j < 4; ++j) {
                int tok = mt * 16 + lg * 4 + j;
                if (tok < 98)
                    out[tok * 104 + h * 32 + nt2 * 16 + l16] = f2bf(acc[j] * inv[j]);
            }
        }
    }
    __syncthreads();

    // ---------- phase 4: proj + shortcut + scatter (42 jobs / 3 waves) ----------
    for (int job = wave; job < 42; job += 3) {
        int mt = job / 6, nt = job % 6;
        int cg = nt * 16 + l16;
        f32x4 acc = {0.f, 0.f, 0.f, 0.f};
        #pragma unroll
        for (int k0 = 0; k0 < 3; ++k0) {
            bf16x8 ao = *(const bf16x8*)(out + (mt * 16 + l16) * 104 + k0 * 32 + lg * 8);
            bf16x8 bp = *(const bf16x8*)(wprojP + ((nt * 3 + k0) << 9) + lane * 8);
            acc = MFMA16(ao, bp, acc);
        }
        float pb = proj_b[cg];
        #pragma unroll
        for (int j = 0; j < 4; ++j) {
            int tok = mt * 16 + lg * 4 + j;
            if (tok < 98) {
                int g = tokbase[tok] + cg;
                dout[g] = x[g] + acc[j] + pb;
            }
        }
    }
}

// ---------------- K3: LN2 + MLP + residual (in-place on d_out), 512 threads ----------------
__global__ __launch_bounds__(512, 2) void mlp_kernel(
    float* __restrict__ xres, const float* __restrict__ w2, const float* __restrict__ b2,
    const ushort_t* __restrict__ wfc1P, const float* __restrict__ fc1_b,
    const ushort_t* __restrict__ wfc2P, const float* __restrict__ fc2_b)
{
    __shared__ ushort_t A_ln[64 * 104];
    __shared__ ushort_t h_lds[64 * 392];
    const int tid = threadIdx.x;
    const int lane = tid & 63, wave = tid >> 6;
    const int l16 = lane & 15, lg = lane >> 4;
    const size_t t0 = (size_t)blockIdx.x * 64;

    {
        int t = tid >> 3, sub = tid & 7;
        const float* xp = xres + (t0 + t) * 96;
        f32x4 v[3];
        float s = 0.f, sq = 0.f;
        #pragma unroll
        for (int j4 = 0; j4 < 3; ++j4) {
            v[j4] = *(const f32x4*)(xp + (j4 * 8 + sub) * 4);
            #pragma unroll
            for (int e = 0; e < 4; ++e) { s += v[j4][e]; sq += v[j4][e] * v[j4][e]; }
        }
        s += __shfl_xor(s, 1); s += __shfl_xor(s, 2); s += __shfl_xor(s, 4);
        sq += __shfl_xor(sq, 1); sq += __shfl_xor(sq, 2); sq += __shfl_xor(sq, 4);
        float mean = s * (1.0f / 96.0f);
        float var = sq * (1.0f / 96.0f) - mean * mean;
        float rs = rsqrtf(var + 1e-5f);
        #pragma unroll
        for (int j4 = 0; j4 < 3; ++j4) {
            int c0 = (j4 * 8 + sub) * 4;
            us4 pk;
            #pragma unroll
            for (int e = 0; e < 4; ++e)
                pk[e] = f2bf((v[j4][e] - mean) * rs * w2[c0 + e] + b2[c0 + e]);
            *(us4*)(A_ln + t * 104 + c0) = pk;
        }
    }
    __syncthreads();

    for (int job = wave; job < 96; job += 8) {
        int mt = job / 24, nt = job % 24;
        int n = nt * 16 + l16;
        f32x4 acc = {0.f, 0.f, 0.f, 0.f};
        #pragma unroll
        for (int k0 = 0; k0 < 3; ++k0) {
            bf16x8 a  = *(const bf16x8*)(A_ln + (mt * 16 + l16) * 104 + k0 * 32 + lg * 8);
            bf16x8 bw = *(const bf16x8*)(wfc1P + ((nt * 3 + k0) << 9) + lane * 8);
            acc = MFMA16(a, bw, acc);
        }
        float bv = fc1_b[n];
        #pragma unroll
        for (int j = 0; j < 4; ++j) {
            int tok = mt * 16 + lg * 4 + j;
            h_lds[tok * 392 + n] = f2bf(gelu_fast(acc[j] + bv));
        }
    }
    __syncthreads();

    for (int job = wave; job < 24; job += 8) {
        int mt = job / 6, nt = job % 6;
        int c = nt * 16 + l16;
        f32x4 acc = {0.f, 0.f, 0.f, 0.f};
        #pragma unroll
        for (int k0 = 0; k0 < 12; ++k0) {
            bf16x8 a  = *(const bf16x8*)(h_lds + (mt * 16 + l16) * 392 + k0 * 32 + lg * 8);
            bf16x8 bw = *(const bf16x8*)(wfc2P + ((nt * 12 + k0) << 9) + lane * 8);
            acc = MFMA16(a, bw, acc);
        }
        float bv = fc2_b[c];
        #pragma unroll
        for (int j = 0; j < 4; ++j) {
            int tok = mt * 16 + lg * 4 + j;
            size_t g = (t0 + tok) * 96 + c;
            xres[g] = xres[g] + acc[j] + bv;
        }
    }
}

// ---------------- launcher ----------------
extern "C" void kernel_launch(void* const* d_in, const int* in_sizes, int n_in,
                              void* d_out, int out_size, void* d_ws, size_t ws_size,
                              hipStream_t stream) {
    const float* x      = (const float*)d_in[0];
    const float* mask   = (const float*)d_in[1];
    const float* n1w    = (const float*)d_in[2];
    const float* n1b    = (const float*)d_in[3];
    const float* qkv_w  = (const float*)d_in[4];
    const float* qkv_b  = (const float*)d_in[5];
    const float* rpb    = (const float*)d_in[6];
    const float* proj_w = (const float*)d_in[7];
    const float* proj_b = (const float*)d_in[8];
    const float* n2w    = (const float*)d_in[9];
    const float* n2b    = (const float*)d_in[10];
    const float* fc1_w  = (const float*)d_in[11];
    const float* fc1_b  = (const float*)d_in[12];
    const float* fc2_w  = (const float*)d_in[13];
    const float* fc2_b  = (const float*)d_in[14];

    char* ws = (char*)d_ws;
    ushort_t* wqkvP  = (ushort_t*)(ws + WQKVP_OFF);
    ushort_t* wprojP = (ushort_t*)(ws + WPROJP_OFF);
    ushort_t* wfc1P  = (ushort_t*)(ws + WFC1P_OFF);
    ushort_t* wfc2P  = (ushort_t*)(ws + WFC2P_OFF);
    float*    biasp  = (float*)(ws + BIAS_OFF);
    float*    dout   = (float*)d_out;

    prep_kernel<<<545, 256, 0, stream>>>(qkv_w, proj_w, fc1_w, fc2_w, rpb,
                                         wqkvP, wprojP, wfc1P, wfc2P, biasp);
    fused_attn<<<4096, 192, 0, stream>>>(x, mask, n1w, n1b, qkv_b, proj_b,
                                         wqkvP, wprojP, biasp, dout);
    mlp_kernel<<<6272, 512, 0, stream>>>(dout, n2w, n2b, wfc1P, fc1_b, wfc2P, fc2_b);
}